// Round 2
// baseline (548.514 us; speedup 1.0000x reference)
//
#include <hip/hip_runtime.h>
#include <hip/hip_bf16.h>

// RGCN 3-layer forward on MI355X — R6: operand-swapped GEMM epilogue.
//   MFMA A-operand = weight rows (BT), B-operand = node rows -> D[wcol][node]:
//   each lane's 4 acc regs = 4 CONSECUTIVE weight-cols of one node ->
//   packed 8 B global_store_dwordx2 epilogue (24 stores/thread vs 96 scalar
//   ushort stores in R4/R5 — the hidden ~45 us cost both shared).
//   BN=192 (1152 = 6x192, no padding). 4-deep LDS ring, BK=32, 1 phase/K-tile:
//   {ds_read 10 frags | stage A,B slab j+3 | lgkmcnt(0) | 24 MFMA |
//    vmcnt(8/4/0) | barrier}. Bs slabs padded to 256 rows so every wave
//   stages exactly 4 loads/K-tile (uniform per-wave vmcnt ledger).
//   Rest unchanged: CSR preprocess, fused [root|W0|W1] B^T, wave-per-node agg.

#define D 384
#define NC 1152      // weight cols total = TC row stride
#define BM 256       // nodes per block
#define BN 192       // weight cols per block (NC/6)
#define BK 32
#define NKT (D / BK)   // 12 K-tiles
#define NTN (NC / BN)  // 6 N-tiles

typedef __attribute__((ext_vector_type(8))) short short8;
typedef __attribute__((ext_vector_type(4))) float floatx4;
typedef unsigned int uint;
typedef unsigned short ushort;

#define BAR() asm volatile("s_barrier" ::: "memory")
#define WAIT_LGKM0() asm volatile("s_waitcnt lgkmcnt(0)" ::: "memory")
#define WAIT_VM8() asm volatile("s_waitcnt vmcnt(8)" ::: "memory")
#define WAIT_VM4() asm volatile("s_waitcnt vmcnt(4)" ::: "memory")
#define WAIT_VM0() asm volatile("s_waitcnt vmcnt(0)" ::: "memory")

__device__ __forceinline__ void load_lds16(const void* g, void* l) {
    __builtin_amdgcn_global_load_lds(
        (const __attribute__((address_space(1))) void*)g,
        (__attribute__((address_space(3))) void*)l, 16, 0, 0);
}

__device__ __forceinline__ ushort f2bf(float x) {
    __hip_bfloat16 h = __float2bfloat16(x);
    return *reinterpret_cast<ushort*>(&h);
}

__device__ __forceinline__ uint pack2(float a, float b) {
    return (uint)f2bf(a) | ((uint)f2bf(b) << 16);
}

// Stage one 256x32 bf16 slab (16 KB) = 2 x global_load_lds_dwordx4 / thread.
// LDS linear chunk (row, cs) <- global chunk (row, cs ^ ((row>>1)&3)).
__device__ __forceinline__ void stage_tile(const ushort* __restrict__ g,
                                           ushort* l, int grow0, int kt,
                                           int rmax, int tid)
{
#pragma unroll
    for (int j = 0; j < 2; ++j) {
        const int ch = j * 512 + tid;          // 0..1023
        const int row = ch >> 2;               // 0..255
        const int cs = ch & 3;                 // slot chunk in 64 B row
        const int gc = cs ^ ((row >> 1) & 3);  // global chunk
        const int gr = min(grow0 + row, rmax); // clamp partial tile
        load_lds16(g + (size_t)gr * D + kt * BK + gc * 8, l + (size_t)ch * 8);
    }
}

// ---- bf16 MFMA GEMM: C[M,NC] = A[M,D] @ BT[NC,D]^T, operand-swapped ----
__global__ __launch_bounds__(512, 2) void gemm_bf16_mfma(
    const ushort* __restrict__ A, const ushort* __restrict__ BT,
    ushort* __restrict__ C, int M, int nwg)
{
    __shared__ alignas(16) ushort As[4][BM * BK];   // node rows,  64 KB ring
    __shared__ alignas(16) ushort Bs[4][BM * BK];   // weight rows (192 used,
                                                    //  staged 256), 64 KB ring

    // bijective XCD-aware remap (m204): each XCD gets contiguous wg range
    const int o = blockIdx.x;
    const int xcd = o & 7, lid = o >> 3;
    const int q = nwg >> 3, r = nwg & 7;
    const int wg = (xcd < r ? xcd * (q + 1) : r * (q + 1) + (xcd - r) * q) + lid;
    const int bnt = wg % NTN, bmt = wg / NTN;
    const int bm = bmt * BM, bn = bnt * BN;

    const int tid = threadIdx.x;
    const int wave = tid >> 6, lane = tid & 63;
    const int wn = wave >> 2;      // n-half 0..1 (96 weight cols each)
    const int wm = wave & 3;       // m-quarter 0..3 (64 nodes each)
    const int l15 = lane & 15, k8 = lane >> 4;

    floatx4 acc[6][4] = {};        // acc[nf][mf]: D[wcol][node]

    // prologue: stage K-tiles 0,1,2 (12 loads/wave); wait until kt0 landed
    stage_tile(A, As[0], bm, 0, M - 1, tid);
    stage_tile(BT, Bs[0], bn, 0, NC - 1, tid);
    stage_tile(A, As[1], bm, 1, M - 1, tid);
    stage_tile(BT, Bs[1], bn, 1, NC - 1, tid);
    stage_tile(A, As[2], bm, 2, M - 1, tid);
    stage_tile(BT, Bs[2], bn, 2, NC - 1, tid);
    WAIT_VM8();
    BAR();

    for (int j = 0; j < NKT; ++j) {
        const ushort* Ab = As[j & 3];
        const ushort* Bb = Bs[j & 3];

        short8 af[6], bf[4];
#pragma unroll
        for (int nf = 0; nf < 6; ++nf) {       // A-operand = weight rows
            const int rr = wn * 96 + nf * 16 + l15;
            af[nf] = *(const short8*)(Bb + rr * BK + ((k8 ^ ((rr >> 1) & 3)) << 3));
        }
#pragma unroll
        for (int mf = 0; mf < 4; ++mf) {       // B-operand = node rows
            const int rr = wm * 64 + mf * 16 + l15;
            bf[mf] = *(const short8*)(Ab + rr * BK + ((k8 ^ ((rr >> 1) & 3)) << 3));
        }

        const int js = j + 3;
        if (js < NKT) {                        // into slot of tile j-1 (freed)
            stage_tile(A, As[js & 3], bm, js, M - 1, tid);
            stage_tile(BT, Bs[js & 3], bn, js, NC - 1, tid);
        }

        WAIT_LGKM0();
        __builtin_amdgcn_sched_barrier(0);
        __builtin_amdgcn_s_setprio(1);
#pragma unroll
        for (int nf = 0; nf < 6; ++nf)
#pragma unroll
            for (int mf = 0; mf < 4; ++mf)
                acc[nf][mf] = __builtin_amdgcn_mfma_f32_16x16x32_bf16(
                    af[nf], bf[mf], acc[nf][mf], 0, 0, 0);
        __builtin_amdgcn_s_setprio(0);

        // counted drain: guarantee K-tile j+1 landed; keep j+2, j+3 in flight
        if (j <= NKT - 4)      { WAIT_VM8(); }
        else if (j == NKT - 3) { WAIT_VM4(); }
        else if (j == NKT - 2) { WAIT_VM0(); }
        BAR();
    }

    // epilogue: lane (k8,l15) of frag (nf,mf) holds weight-cols
    // bn + wn*96 + nf*16 + k8*4 + {0..3} of node bm + wm*64 + mf*16 + l15
    // -> one 8 B packed store per frag per lane.
    const int node0 = bm + wm * 64 + l15;
    const int col0 = bn + wn * 96 + k8 * 4;
    if (bm + BM <= M) {
#pragma unroll
        for (int mf = 0; mf < 4; ++mf) {
            uint2* rowp = (uint2*)(C + (size_t)(node0 + mf * 16) * NC + col0);
#pragma unroll
            for (int nf = 0; nf < 6; ++nf) {
                uint2 o2;
                o2.x = pack2(acc[nf][mf][0], acc[nf][mf][1]);
                o2.y = pack2(acc[nf][mf][2], acc[nf][mf][3]);
                rowp[nf * 4] = o2;             // nf*16 cols = 4 uint2
            }
        }
    } else {
#pragma unroll
        for (int mf = 0; mf < 4; ++mf) {
            const int node = node0 + mf * 16;
            if (node < M) {
                uint2* rowp = (uint2*)(C + (size_t)node * NC + col0);
#pragma unroll
                for (int nf = 0; nf < 6; ++nf) {
                    uint2 o2;
                    o2.x = pack2(acc[nf][mf][0], acc[nf][mf][1]);
                    o2.y = pack2(acc[nf][mf][2], acc[nf][mf][3]);
                    rowp[nf * 4] = o2;
                }
            }
        }
    }
}

// ---- preprocessing: CSR by (rel, dst) ----

__global__ __launch_bounds__(256) void count_edges(
    const int* __restrict__ dst, const int* __restrict__ et,
    int* __restrict__ cntI, int E, int M)
{
    const int e = blockIdx.x * blockDim.x + threadIdx.x;
    if (e < E) atomicAdd(&cntI[(size_t)et[e] * M + dst[e]], 1);
}

__global__ __launch_bounds__(256) void finalize_cnt(
    const int* __restrict__ cntI, float* __restrict__ invc, int n)
{
    const int i = blockIdx.x * blockDim.x + threadIdx.x;
    if (i < n) invc[i] = 1.0f / (float)max(cntI[i], 1);
}

// ---- 3-kernel hierarchical exclusive scan (n ~ 100k) ----
__global__ __launch_bounds__(1024) void scan_local(
    const int* __restrict__ hist, int* __restrict__ offs,
    int* __restrict__ bsums, int n)
{
    __shared__ int tmp[1024];
    const int tid = threadIdx.x;
    const int i = blockIdx.x * 1024 + tid;
    const int v = (i < n) ? hist[i] : 0;
    tmp[tid] = v;
    __syncthreads();
#pragma unroll
    for (int off = 1; off < 1024; off <<= 1) {
        const int add = (tid >= off) ? tmp[tid - off] : 0;
        __syncthreads();
        tmp[tid] += add;
        __syncthreads();
    }
    if (i < n) offs[i] = tmp[tid] - v;
    if (tid == 1023) bsums[blockIdx.x] = tmp[1023];
}

__global__ __launch_bounds__(1024) void scan_bsums(
    int* __restrict__ bsums, int* __restrict__ total_out, int nb)
{
    __shared__ int tmp[1024];
    const int tid = threadIdx.x;
    const int v = (tid < nb) ? bsums[tid] : 0;
    tmp[tid] = v;
    __syncthreads();
#pragma unroll
    for (int off = 1; off < 1024; off <<= 1) {
        const int add = (tid >= off) ? tmp[tid - off] : 0;
        __syncthreads();
        tmp[tid] += add;
        __syncthreads();
    }
    if (tid < nb) bsums[tid] = tmp[tid] - v;
    if (tid == 1023) *total_out = tmp[1023];
}

__global__ __launch_bounds__(1024) void scan_add(
    int* __restrict__ offs, const int* __restrict__ bsums, int n)
{
    const int i = blockIdx.x * 1024 + threadIdx.x;
    if (i < n) offs[i] += bsums[blockIdx.x];
}

__global__ __launch_bounds__(256) void fill_sorted(
    const int* __restrict__ src, const int* __restrict__ dst,
    const int* __restrict__ et, const int* __restrict__ offs,
    int* __restrict__ cursor, int* __restrict__ sorted, int E, int M)
{
    const int e = blockIdx.x * blockDim.x + threadIdx.x;
    if (e < E) {
        const int key = et[e] * M + dst[e];
        const int pos = offs[key] + atomicAdd(&cursor[key], 1);
        sorted[pos] = src[e];
    }
}

// ---- weights -> concatenated B^T bf16 [NC, D] per layer ----
__global__ __launch_bounds__(256) void build_bt(
    const float* __restrict__ root1, const float* __restrict__ W1,
    const float* __restrict__ root2, const float* __restrict__ W2,
    const float* __restrict__ root3, const float* __restrict__ W3,
    ushort* __restrict__ BT)
{
    __shared__ float tile[32][33];
    const int l = blockIdx.z;
    const float* root = (l == 0) ? root1 : (l == 1) ? root2 : root3;
    const float* W    = (l == 0) ? W1    : (l == 1) ? W2    : W3;
    const int kt = blockIdx.x * 32;
    const int nt = blockIdx.y * 32;
    const int tx = threadIdx.x & 31;
    const int ty = threadIdx.x >> 5;
    const float* srcm;
    int noff;
    if (nt < D)          { srcm = root;      noff = 0; }
    else if (nt < 2 * D) { srcm = W;         noff = D; }
    else                 { srcm = W + D * D; noff = 2 * D; }
    const int n = nt - noff + tx;
#pragma unroll
    for (int i = 0; i < 4; ++i) {
        const int k = kt + ty + i * 8;
        tile[ty + i * 8][tx] = srcm[(size_t)k * D + n];
    }
    __syncthreads();
    ushort* dst = BT + (size_t)l * NC * D;
#pragma unroll
    for (int i = 0; i < 4; ++i) {
        const int nn = nt + ty + i * 8;
        const int kk = kt + tx;
        dst[(size_t)nn * D + kk] = f2bf(tile[tx][ty + i * 8]);
    }
}

__global__ __launch_bounds__(256) void cast_f32_to_bf16(
    const float* __restrict__ x, ushort* __restrict__ y, int n4)
{
    const int i = blockIdx.x * blockDim.x + threadIdx.x;
    if (i < n4) {
        const float4 v = ((const float4*)x)[i];
        uint2 o;
        o.x = pack2(v.x, v.y);
        o.y = pack2(v.z, v.w);
        ((uint2*)y)[i] = o;
    }
}

// ---- fused aggregation: one wave per node, both relations + root + bias ----
__global__ __launch_bounds__(256) void aggregate_all(
    const ushort* __restrict__ TC, const int* __restrict__ sorted,
    const int* __restrict__ offs, const float* __restrict__ invc,
    const float* __restrict__ bias, ushort* __restrict__ outb,
    float* __restrict__ outf, int M, int relu)
{
    const int wave = threadIdx.x >> 6;
    const int lane = threadIdx.x & 63;
    const int d = blockIdx.x * 4 + wave;
    if (d >= M) return;

    float v[6];
    {
        const uint* rp = (const uint*)(TC + (size_t)d * NC);
#pragma unroll
        for (int p = 0; p < 3; ++p) {
            const uint b = rp[lane + 64 * p];
            const float2 bb = *(const float2*)(bias + (lane + 64 * p) * 2);
            v[2 * p]     = __uint_as_float(b << 16) + bb.x;
            v[2 * p + 1] = __uint_as_float(b & 0xffff0000u) + bb.y;
        }
    }
#pragma unroll
    for (int r = 0; r < 2; ++r) {
        const int key = r * M + d;
        const int beg = offs[key], end = offs[key + 1];
        float g[6] = {0.f, 0.f, 0.f, 0.f, 0.f, 0.f};
        for (int i = beg; i < end; ++i) {
            const int s = sorted[i];
            const uint* tp = (const uint*)(TC + (size_t)s * NC + D + r * D);
#pragma unroll
            for (int p = 0; p < 3; ++p) {
                const uint b = tp[lane + 64 * p];
                g[2 * p]     += __uint_as_float(b << 16);
                g[2 * p + 1] += __uint_as_float(b & 0xffff0000u);
            }
        }
        const float ic = invc[key];
#pragma unroll
        for (int j = 0; j < 6; ++j) v[j] += ic * g[j];
    }
    if (relu) {
#pragma unroll
        for (int j = 0; j < 6; ++j) v[j] = fmaxf(v[j], 0.f);
    }
    if (outb) {
        uint* op = (uint*)(outb + (size_t)d * D);
#pragma unroll
        for (int p = 0; p < 3; ++p) op[lane + 64 * p] = pack2(v[2 * p], v[2 * p + 1]);
    } else {
        float2* op = (float2*)(outf + (size_t)d * D);
#pragma unroll
        for (int p = 0; p < 3; ++p)
            op[lane + 64 * p] = make_float2(v[2 * p], v[2 * p + 1]);
    }
}

extern "C" void kernel_launch(void* const* d_in, const int* in_sizes, int n_in,
                              void* d_out, int out_size, void* d_ws, size_t ws_size,
                              hipStream_t stream)
{
    const float* emb   = (const float*)d_in[0];
    const int*   eidx  = (const int*)d_in[1];
    const int*   et    = (const int*)d_in[2];
    const float* W1    = (const float*)d_in[3];
    const float* root1 = (const float*)d_in[4];
    const float* bias1 = (const float*)d_in[5];
    const float* W2    = (const float*)d_in[6];
    const float* root2 = (const float*)d_in[7];
    const float* bias2 = (const float*)d_in[8];
    const float* W3    = (const float*)d_in[9];
    const float* root3 = (const float*)d_in[10];
    const float* bias3 = (const float*)d_in[11];

    float* out = (float*)d_out;
    const int M = in_sizes[0] / D;   // 50000
    const int E = in_sizes[1] / 2;   // 200000
    const int* src  = eidx;
    const int* dstv = eidx + E;

    const int n = 2 * M;
    const int nb = (n + 1023) / 1024;

    // Workspace: TC[M*NC]bf16 | Xb[M*D]bf16 | BT[3*NC*D]bf16 |
    //            invcnt[2M]f32 | cntI[2M]i32 | offs[2M+1]i32 | sorted[E]i32 |
    //            bsums[nb]i32
    char* w = (char*)d_ws;
    ushort* TC = (ushort*)w;          w += (size_t)M * NC * 2;
    ushort* Xb = (ushort*)w;          w += (size_t)M * D * 2;
    ushort* BT = (ushort*)w;          w += (size_t)3 * NC * D * 2;
    float* invcnt = (float*)w;        w += (size_t)n * 4;
    int* cntI = (int*)w;              w += (size_t)n * 4;
    int* offs = (int*)w;              w += ((size_t)n + 1) * 4;
    int* sorted = (int*)w;            w += (size_t)E * 4;
    int* bsums = (int*)w;

    // --- preprocessing ---
    hipMemsetAsync(cntI, 0, (size_t)n * sizeof(int), stream);
    count_edges<<<(E + 255) / 256, 256, 0, stream>>>(dstv, et, cntI, E, M);
    finalize_cnt<<<(n + 255) / 256, 256, 0, stream>>>(cntI, invcnt, n);
    scan_local<<<nb, 1024, 0, stream>>>(cntI, offs, bsums, n);
    scan_bsums<<<1, 1024, 0, stream>>>(bsums, offs + n, nb);
    scan_add<<<nb, 1024, 0, stream>>>(offs, bsums, n);
    hipMemsetAsync(cntI, 0, (size_t)n * sizeof(int), stream);
    fill_sorted<<<(E + 255) / 256, 256, 0, stream>>>(src, dstv, et, offs, cntI, sorted, E, M);

    build_bt<<<dim3(D / 32, NC / 32, 3), 256, 0, stream>>>(root1, W1, root2, W2, root3, W3, BT);
    cast_f32_to_bf16<<<(M * D / 4 + 255) / 256, 256, 0, stream>>>(emb, Xb, M * D / 4);

    // GEMM grid: 196 M-tiles x 6 N-tiles, bijective XCD swizzle in-kernel
    const int Mtiles = (M + BM - 1) / BM;
    const int nwg = Mtiles * NTN;
    const float* biases[3] = {bias1, bias2, bias3};
    for (int l = 0; l < 3; ++l) {
        gemm_bf16_mfma<<<nwg, 512, 0, stream>>>(Xb, BT + (size_t)l * NC * D, TC, M, nwg);
        const bool last = (l == 2);
        aggregate_all<<<(M + 3) / 4, 256, 0, stream>>>(
            TC, sorted, offs, invcnt, biases[l],
            last ? nullptr : Xb, last ? out : nullptr, M, last ? 0 : 1);
    }
}

// Round 3
// 510.496 us; speedup vs baseline: 1.0745x; 1.0745x over previous
//
#include <hip/hip_runtime.h>
#include <hip/hip_bf16.h>

// RGCN 3-layer forward on MI355X — R7: TLP GEMM (2 blocks/CU).
//   Diagnosis R4-R6: all schedules ~75-85 us because per-CU phase costs
//   (MFMA 21 us, LDS reads ~20, L2 staging ~17, stores 6-23) run SERIALLY:
//   1 block/CU + full-block barriers => ds_read and MFMA phases alternate.
//   Fix: 2 independent blocks per CU. BM=256 BN=128 BK=32, 3-deep LDS ring
//   (72 KB -> 2 blocks fit in 160 KB), 8 waves of 64x64 wave-tile
//   (acc 64 + frags 32 VGPR, __launch_bounds__(512,4) caps at 128 -> 16
//   waves/CU). Counted vmcnt(3): 2 tiles in flight, 3 load-instrs/tile.
//   Operand-swapped epilogue (weights=A-operand, proven in R6) -> 8 B
//   packed stores. Zero-conflict chunk swizzle cs^((row>>1)&3) kept.
//   Rest unchanged: CSR preprocess, fused [root|W0|W1] B^T, wave-per-node agg.

#define D 384
#define NC 1152      // weight cols total = TC row stride
#define BM 256       // nodes per block
#define BN 128       // weight cols per block (NC/9)
#define BK 32
#define NKT (D / BK)   // 12 K-tiles
#define NTN (NC / BN)  // 9 N-tiles

typedef __attribute__((ext_vector_type(8))) short short8;
typedef __attribute__((ext_vector_type(4))) float floatx4;
typedef unsigned int uint;
typedef unsigned short ushort;

#define BAR() asm volatile("s_barrier" ::: "memory")
#define WAIT_VM3() asm volatile("s_waitcnt vmcnt(3)" ::: "memory")
#define WAIT_VM0() asm volatile("s_waitcnt vmcnt(0)" ::: "memory")

__device__ __forceinline__ void load_lds16(const void* g, void* l) {
    __builtin_amdgcn_global_load_lds(
        (const __attribute__((address_space(1))) void*)g,
        (__attribute__((address_space(3))) void*)l, 16, 0, 0);
}

__device__ __forceinline__ ushort f2bf(float x) {
    __hip_bfloat16 h = __float2bfloat16(x);
    return *reinterpret_cast<ushort*>(&h);
}

__device__ __forceinline__ uint pack2(float a, float b) {
    return (uint)f2bf(a) | ((uint)f2bf(b) << 16);
}

// Stage 256x32 bf16 slab (16 KB) = 2 x global_load_lds_dwordx4 / thread.
// LDS linear chunk (row, cs) <- global chunk (row, cs ^ ((row>>1)&3)).
__device__ __forceinline__ void stage_a(const ushort* __restrict__ g,
                                        ushort* l, int grow0, int kt,
                                        int rmax, int tid)
{
#pragma unroll
    for (int j = 0; j < 2; ++j) {
        const int ch = j * 512 + tid;          // 0..1023
        const int row = ch >> 2;               // 0..255
        const int cs = ch & 3;                 // slot chunk in 64 B row
        const int gc = cs ^ ((row >> 1) & 3);  // global chunk
        const int gr = min(grow0 + row, rmax); // clamp partial tile
        load_lds16(g + (size_t)gr * D + kt * BK + gc * 8, l + (size_t)ch * 8);
    }
}

// Stage 128x32 bf16 slab (8 KB) = 1 x global_load_lds_dwordx4 / thread.
__device__ __forceinline__ void stage_b(const ushort* __restrict__ g,
                                        ushort* l, int grow0, int kt, int tid)
{
    const int row = tid >> 2;                  // 0..127
    const int cs = tid & 3;
    const int gc = cs ^ ((row >> 1) & 3);
    load_lds16(g + (size_t)(grow0 + row) * D + kt * BK + gc * 8,
               l + (size_t)tid * 8);
}

// ---- bf16 MFMA GEMM: C[M,NC] = A[M,D] @ BT[NC,D]^T, operand-swapped ----
__global__ __launch_bounds__(512, 4) void gemm_bf16_mfma(
    const ushort* __restrict__ A, const ushort* __restrict__ BT,
    ushort* __restrict__ C, int M, int nwg)
{
    __shared__ alignas(16) ushort As[3][BM * BK];   // node rows,   48 KB ring
    __shared__ alignas(16) ushort Bs[3][BN * BK];   // weight rows, 24 KB ring

    // bijective XCD-aware remap (m204): each XCD gets contiguous wg range;
    // the 9 N-tiles of an M-tile stay consecutive -> A-panel L2 reuse.
    const int o = blockIdx.x;
    const int xcd = o & 7, lid = o >> 3;
    const int q = nwg >> 3, r = nwg & 7;
    const int wg = (xcd < r ? xcd * (q + 1) : r * (q + 1) + (xcd - r) * q) + lid;
    const int bnt = wg % NTN, bmt = wg / NTN;
    const int bm = bmt * BM, bn = bnt * BN;

    const int tid = threadIdx.x;
    const int wave = tid >> 6, lane = tid & 63;
    const int wm = wave >> 1;      // m-quarter 0..3 (64 nodes each)
    const int wn = wave & 1;       // n-half 0..1 (64 weight cols each)
    const int l15 = lane & 15, k8 = lane >> 4;

    floatx4 acc[4][4] = {};        // acc[nf][mf]: D[wcol][node]

    // prologue: stage K-tiles 0,1 (6 load-instrs/wave); wait kt0 landed
    stage_a(A, As[0], bm, 0, M - 1, tid);
    stage_b(BT, Bs[0], bn, 0, tid);
    stage_a(A, As[1], bm, 1, M - 1, tid);
    stage_b(BT, Bs[1], bn, 1, tid);
    WAIT_VM3();
    BAR();

    for (int j = 0; j < NKT; ++j) {
        const ushort* Ab = As[j % 3];
        const ushort* Bb = Bs[j % 3];

        short8 af[4], bf[4];
#pragma unroll
        for (int nf = 0; nf < 4; ++nf) {       // A-operand = weight rows
            const int rr = wn * 64 + nf * 16 + l15;
            af[nf] = *(const short8*)(Bb + rr * BK + ((k8 ^ ((rr >> 1) & 3)) << 3));
        }
#pragma unroll
        for (int mf = 0; mf < 4; ++mf) {       // B-operand = node rows
            const int rr = wm * 64 + mf * 16 + l15;
            bf[mf] = *(const short8*)(Ab + rr * BK + ((k8 ^ ((rr >> 1) & 3)) << 3));
        }

        const int js = j + 2;
        if (js < NKT) {                        // slot of tile j-1 (read done)
            stage_a(A, As[js % 3], bm, js, M - 1, tid);
            stage_b(BT, Bs[js % 3], bn, js, tid);
        }

        __builtin_amdgcn_s_setprio(1);
#pragma unroll
        for (int nf = 0; nf < 4; ++nf)
#pragma unroll
            for (int mf = 0; mf < 4; ++mf)
                acc[nf][mf] = __builtin_amdgcn_mfma_f32_16x16x32_bf16(
                    af[nf], bf[mf], acc[nf][mf], 0, 0, 0);
        __builtin_amdgcn_s_setprio(0);

        // counted drain: tile j+1 landed; keep tile j+2's 3 loads in flight
        if (j <= NKT - 3)      { WAIT_VM3(); }
        else if (j == NKT - 2) { WAIT_VM0(); }
        BAR();
    }

    // epilogue: lane (k8,l15) of frag (nf,mf) holds weight-cols
    // bn + wn*64 + nf*16 + k8*4 + {0..3} of node bm + wm*64 + mf*16 + l15
    const int node0 = bm + wm * 64 + l15;
    const int col0 = bn + wn * 64 + k8 * 4;
    if (bm + BM <= M) {
#pragma unroll
        for (int mf = 0; mf < 4; ++mf) {
            uint2* rowp = (uint2*)(C + (size_t)(node0 + mf * 16) * NC + col0);
#pragma unroll
            for (int nf = 0; nf < 4; ++nf) {
                uint2 o2;
                o2.x = pack2(acc[nf][mf][0], acc[nf][mf][1]);
                o2.y = pack2(acc[nf][mf][2], acc[nf][mf][3]);
                rowp[nf * 4] = o2;             // nf*16 cols = 4 uint2
            }
        }
    } else {
#pragma unroll
        for (int mf = 0; mf < 4; ++mf) {
            const int node = node0 + mf * 16;
            if (node < M) {
                uint2* rowp = (uint2*)(C + (size_t)node * NC + col0);
#pragma unroll
                for (int nf = 0; nf < 4; ++nf) {
                    uint2 o2;
                    o2.x = pack2(acc[nf][mf][0], acc[nf][mf][1]);
                    o2.y = pack2(acc[nf][mf][2], acc[nf][mf][3]);
                    rowp[nf * 4] = o2;
                }
            }
        }
    }
}

// ---- preprocessing: CSR by (rel, dst) ----

__global__ __launch_bounds__(256) void count_edges(
    const int* __restrict__ dst, const int* __restrict__ et,
    int* __restrict__ cntI, int E, int M)
{
    const int e = blockIdx.x * blockDim.x + threadIdx.x;
    if (e < E) atomicAdd(&cntI[(size_t)et[e] * M + dst[e]], 1);
}

__global__ __launch_bounds__(256) void finalize_cnt(
    const int* __restrict__ cntI, float* __restrict__ invc, int n)
{
    const int i = blockIdx.x * blockDim.x + threadIdx.x;
    if (i < n) invc[i] = 1.0f / (float)max(cntI[i], 1);
}

// ---- 3-kernel hierarchical exclusive scan (n ~ 100k) ----
__global__ __launch_bounds__(1024) void scan_local(
    const int* __restrict__ hist, int* __restrict__ offs,
    int* __restrict__ bsums, int n)
{
    __shared__ int tmp[1024];
    const int tid = threadIdx.x;
    const int i = blockIdx.x * 1024 + tid;
    const int v = (i < n) ? hist[i] : 0;
    tmp[tid] = v;
    __syncthreads();
#pragma unroll
    for (int off = 1; off < 1024; off <<= 1) {
        const int add = (tid >= off) ? tmp[tid - off] : 0;
        __syncthreads();
        tmp[tid] += add;
        __syncthreads();
    }
    if (i < n) offs[i] = tmp[tid] - v;
    if (tid == 1023) bsums[blockIdx.x] = tmp[1023];
}

__global__ __launch_bounds__(1024) void scan_bsums(
    int* __restrict__ bsums, int* __restrict__ total_out, int nb)
{
    __shared__ int tmp[1024];
    const int tid = threadIdx.x;
    const int v = (tid < nb) ? bsums[tid] : 0;
    tmp[tid] = v;
    __syncthreads();
#pragma unroll
    for (int off = 1; off < 1024; off <<= 1) {
        const int add = (tid >= off) ? tmp[tid - off] : 0;
        __syncthreads();
        tmp[tid] += add;
        __syncthreads();
    }
    if (tid < nb) bsums[tid] = tmp[tid] - v;
    if (tid == 1023) *total_out = tmp[1023];
}

__global__ __launch_bounds__(1024) void scan_add(
    int* __restrict__ offs, const int* __restrict__ bsums, int n)
{
    const int i = blockIdx.x * 1024 + threadIdx.x;
    if (i < n) offs[i] += bsums[blockIdx.x];
}

__global__ __launch_bounds__(256) void fill_sorted(
    const int* __restrict__ src, const int* __restrict__ dst,
    const int* __restrict__ et, const int* __restrict__ offs,
    int* __restrict__ cursor, int* __restrict__ sorted, int E, int M)
{
    const int e = blockIdx.x * blockDim.x + threadIdx.x;
    if (e < E) {
        const int key = et[e] * M + dst[e];
        const int pos = offs[key] + atomicAdd(&cursor[key], 1);
        sorted[pos] = src[e];
    }
}

// ---- weights -> concatenated B^T bf16 [NC, D] per layer ----
__global__ __launch_bounds__(256) void build_bt(
    const float* __restrict__ root1, const float* __restrict__ W1,
    const float* __restrict__ root2, const float* __restrict__ W2,
    const float* __restrict__ root3, const float* __restrict__ W3,
    ushort* __restrict__ BT)
{
    __shared__ float tile[32][33];
    const int l = blockIdx.z;
    const float* root = (l == 0) ? root1 : (l == 1) ? root2 : root3;
    const float* W    = (l == 0) ? W1    : (l == 1) ? W2    : W3;
    const int kt = blockIdx.x * 32;
    const int nt = blockIdx.y * 32;
    const int tx = threadIdx.x & 31;
    const int ty = threadIdx.x >> 5;
    const float* srcm;
    int noff;
    if (nt < D)          { srcm = root;      noff = 0; }
    else if (nt < 2 * D) { srcm = W;         noff = D; }
    else                 { srcm = W + D * D; noff = 2 * D; }
    const int n = nt - noff + tx;
#pragma unroll
    for (int i = 0; i < 4; ++i) {
        const int k = kt + ty + i * 8;
        tile[ty + i * 8][tx] = srcm[(size_t)k * D + n];
    }
    __syncthreads();
    ushort* dst = BT + (size_t)l * NC * D;
#pragma unroll
    for (int i = 0; i < 4; ++i) {
        const int nn = nt + ty + i * 8;
        const int kk = kt + tx;
        dst[(size_t)nn * D + kk] = f2bf(tile[tx][ty + i * 8]);
    }
}

__global__ __launch_bounds__(256) void cast_f32_to_bf16(
    const float* __restrict__ x, ushort* __restrict__ y, int n4)
{
    const int i = blockIdx.x * blockDim.x + threadIdx.x;
    if (i < n4) {
        const float4 v = ((const float4*)x)[i];
        uint2 o;
        o.x = pack2(v.x, v.y);
        o.y = pack2(v.z, v.w);
        ((uint2*)y)[i] = o;
    }
}

// ---- fused aggregation: one wave per node, both relations + root + bias ----
__global__ __launch_bounds__(256) void aggregate_all(
    const ushort* __restrict__ TC, const int* __restrict__ sorted,
    const int* __restrict__ offs, const float* __restrict__ invc,
    const float* __restrict__ bias, ushort* __restrict__ outb,
    float* __restrict__ outf, int M, int relu)
{
    const int wave = threadIdx.x >> 6;
    const int lane = threadIdx.x & 63;
    const int d = blockIdx.x * 4 + wave;
    if (d >= M) return;

    float v[6];
    {
        const uint* rp = (const uint*)(TC + (size_t)d * NC);
#pragma unroll
        for (int p = 0; p < 3; ++p) {
            const uint b = rp[lane + 64 * p];
            const float2 bb = *(const float2*)(bias + (lane + 64 * p) * 2);
            v[2 * p]     = __uint_as_float(b << 16) + bb.x;
            v[2 * p + 1] = __uint_as_float(b & 0xffff0000u) + bb.y;
        }
    }
#pragma unroll
    for (int r = 0; r < 2; ++r) {
        const int key = r * M + d;
        const int beg = offs[key], end = offs[key + 1];
        float g[6] = {0.f, 0.f, 0.f, 0.f, 0.f, 0.f};
        for (int i = beg; i < end; ++i) {
            const int s = sorted[i];
            const uint* tp = (const uint*)(TC + (size_t)s * NC + D + r * D);
#pragma unroll
            for (int p = 0; p < 3; ++p) {
                const uint b = tp[lane + 64 * p];
                g[2 * p]     += __uint_as_float(b << 16);
                g[2 * p + 1] += __uint_as_float(b & 0xffff0000u);
            }
        }
        const float ic = invc[key];
#pragma unroll
        for (int j = 0; j < 6; ++j) v[j] += ic * g[j];
    }
    if (relu) {
#pragma unroll
        for (int j = 0; j < 6; ++j) v[j] = fmaxf(v[j], 0.f);
    }
    if (outb) {
        uint* op = (uint*)(outb + (size_t)d * D);
#pragma unroll
        for (int p = 0; p < 3; ++p) op[lane + 64 * p] = pack2(v[2 * p], v[2 * p + 1]);
    } else {
        float2* op = (float2*)(outf + (size_t)d * D);
#pragma unroll
        for (int p = 0; p < 3; ++p)
            op[lane + 64 * p] = make_float2(v[2 * p], v[2 * p + 1]);
    }
}

extern "C" void kernel_launch(void* const* d_in, const int* in_sizes, int n_in,
                              void* d_out, int out_size, void* d_ws, size_t ws_size,
                              hipStream_t stream)
{
    const float* emb   = (const float*)d_in[0];
    const int*   eidx  = (const int*)d_in[1];
    const int*   et    = (const int*)d_in[2];
    const float* W1    = (const float*)d_in[3];
    const float* root1 = (const float*)d_in[4];
    const float* bias1 = (const float*)d_in[5];
    const float* W2    = (const float*)d_in[6];
    const float* root2 = (const float*)d_in[7];
    const float* bias2 = (const float*)d_in[8];
    const float* W3    = (const float*)d_in[9];
    const float* root3 = (const float*)d_in[10];
    const float* bias3 = (const float*)d_in[11];

    float* out = (float*)d_out;
    const int M = in_sizes[0] / D;   // 50000
    const int E = in_sizes[1] / 2;   // 200000
    const int* src  = eidx;
    const int* dstv = eidx + E;

    const int n = 2 * M;
    const int nb = (n + 1023) / 1024;

    // Workspace: TC[M*NC]bf16 | Xb[M*D]bf16 | BT[3*NC*D]bf16 |
    //            invcnt[2M]f32 | cntI[2M]i32 | offs[2M+1]i32 | sorted[E]i32 |
    //            bsums[nb]i32
    char* w = (char*)d_ws;
    ushort* TC = (ushort*)w;          w += (size_t)M * NC * 2;
    ushort* Xb = (ushort*)w;          w += (size_t)M * D * 2;
    ushort* BT = (ushort*)w;          w += (size_t)3 * NC * D * 2;
    float* invcnt = (float*)w;        w += (size_t)n * 4;
    int* cntI = (int*)w;              w += (size_t)n * 4;
    int* offs = (int*)w;              w += ((size_t)n + 1) * 4;
    int* sorted = (int*)w;            w += (size_t)E * 4;
    int* bsums = (int*)w;

    // --- preprocessing ---
    hipMemsetAsync(cntI, 0, (size_t)n * sizeof(int), stream);
    count_edges<<<(E + 255) / 256, 256, 0, stream>>>(dstv, et, cntI, E, M);
    finalize_cnt<<<(n + 255) / 256, 256, 0, stream>>>(cntI, invcnt, n);
    scan_local<<<nb, 1024, 0, stream>>>(cntI, offs, bsums, n);
    scan_bsums<<<1, 1024, 0, stream>>>(bsums, offs + n, nb);
    scan_add<<<nb, 1024, 0, stream>>>(offs, bsums, n);
    hipMemsetAsync(cntI, 0, (size_t)n * sizeof(int), stream);
    fill_sorted<<<(E + 255) / 256, 256, 0, stream>>>(src, dstv, et, offs, cntI, sorted, E, M);

    build_bt<<<dim3(D / 32, NC / 32, 3), 256, 0, stream>>>(root1, W1, root2, W2, root3, W3, BT);
    cast_f32_to_bf16<<<(M * D / 4 + 255) / 256, 256, 0, stream>>>(emb, Xb, M * D / 4);

    // GEMM grid: 196 M-tiles x 9 N-tiles, bijective XCD swizzle in-kernel
    const int Mtiles = (M + BM - 1) / BM;
    const int nwg = Mtiles * NTN;
    const float* biases[3] = {bias1, bias2, bias3};
    for (int l = 0; l < 3; ++l) {
        gemm_bf16_mfma<<<nwg, 512, 0, stream>>>(Xb, BT + (size_t)l * NC * D, TC, M, nwg);
        const bool last = (l == 2);
        aggregate_all<<<(M + 3) / 4, 256, 0, stream>>>(
            TC, sorted, offs, invcnt, biases[l],
            last ? nullptr : Xb, last ? out : nullptr, M, last ? 0 : 1);
    }
}

// Round 4
// 487.107 us; speedup vs baseline: 1.1261x; 1.0480x over previous
//
#include <hip/hip_runtime.h>
#include <hip/hip_bf16.h>

// RGCN 3-layer forward on MI355X — R8: aggregate-then-transform restructure.
//   R4-R7 invariant: GEMM pinned at ~77 us, ~1.85 TB/s effective traffic,
//   regardless of schedule/occupancy/epilogue => footprint-capped, dominated
//   by the 115 MB C write. RGCN is linear, so swap the order:
//     out = [X | agg0(X) | agg1(X)] @ [[root],[W0],[W1]] + bias
//   GEMM becomes K=1152, N=384: same 44.2 GFLOP, 3x smaller C (38.4 MB bf16),
//   bias+ReLU fused in epilogue, combine pass of old aggregate_all gone.
//   Aggregation now gathers from the 38.4 MB X table (L2/L3-friendly) and
//   writes AG[M x 768] bf16.
//   GEMM geometry = R7's verified math: BM=BN=128, BK=32, 36 K-tiles,
//   3-deep LDS ring (48 KB -> 3 blocks/CU), 4 waves of 64x64 wave-tile,
//   operand-swapped (weights=A-operand) packed epilogue, counted vmcnt(4),
//   chunk swizzle cs^((row>>1)&3), bijective XCD remap.

#define D 384
#define KC 1152      // concat K = 3*D
#define BM 128       // nodes per block
#define BN 128       // out cols per block (D/3... 384/128=3 tiles)
#define BK 32
#define NKT (KC / BK)  // 36 K-tiles
#define NTN (D / BN)   // 3 N-tiles

typedef __attribute__((ext_vector_type(8))) short short8;
typedef __attribute__((ext_vector_type(4))) float floatx4;
typedef unsigned int uint;
typedef unsigned short ushort;

#define BAR() asm volatile("s_barrier" ::: "memory")
#define WAIT_VM4() asm volatile("s_waitcnt vmcnt(4)" ::: "memory")
#define WAIT_VM0() asm volatile("s_waitcnt vmcnt(0)" ::: "memory")

__device__ __forceinline__ void load_lds16(const void* g, void* l) {
    __builtin_amdgcn_global_load_lds(
        (const __attribute__((address_space(1))) void*)g,
        (__attribute__((address_space(3))) void*)l, 16, 0, 0);
}

__device__ __forceinline__ ushort f2bf(float x) {
    __hip_bfloat16 h = __float2bfloat16(x);
    return *reinterpret_cast<ushort*>(&h);
}

__device__ __forceinline__ uint pack2(float a, float b) {
    return (uint)f2bf(a) | ((uint)f2bf(b) << 16);
}

// Stage one 128x32 bf16 slab (8 KB) = 2 x global_load_lds_dwordx4 / thread
// (256 threads). LDS chunk (row, cs) <- global chunk (row, cs ^ ((row>>1)&3)).
__device__ __forceinline__ void stage_rows(const ushort* __restrict__ g,
                                           size_t stride, int koff,
                                           ushort* l, int grow0, int rmax,
                                           int tid)
{
#pragma unroll
    for (int j = 0; j < 2; ++j) {
        const int ch = j * 256 + tid;          // 0..511
        const int row = ch >> 2;               // 0..127
        const int cs = ch & 3;                 // slot chunk in 64 B row
        const int gc = cs ^ ((row >> 1) & 3);  // global chunk
        const int gr = min(grow0 + row, rmax); // clamp partial tile
        load_lds16(g + (size_t)gr * stride + koff + gc * 8, l + (size_t)ch * 8);
    }
}

// ---- fused GEMM: H[M,D] = [X|AG] @ BT^T + bias (+relu) ----
// X: [M,384] bf16 (K 0..383), AG: [M,768] bf16 (K 384..1151),
// BT: [384 rows][1152 K] bf16. Output: Xn bf16 [M,384] or outf f32 [M,384].
__global__ __launch_bounds__(256, 3) void gemm_fused(
    const ushort* __restrict__ X, const ushort* __restrict__ AG,
    const ushort* __restrict__ BT, const float* __restrict__ bias,
    ushort* __restrict__ Xn, float* __restrict__ outf,
    int M, int nwg, int relu)
{
    __shared__ alignas(16) ushort As[3][BM * BK];   // node rows,   24 KB ring
    __shared__ alignas(16) ushort Bs[3][BN * BK];   // weight rows, 24 KB ring

    // bijective XCD-aware remap (m204): contiguous wg range per XCD;
    // 3 N-tiles of an M-tile consecutive -> A-panel (288 KB) L2 reuse.
    const int o = blockIdx.x;
    const int xcd = o & 7, lid = o >> 3;
    const int q = nwg >> 3, r = nwg & 7;
    const int wg = (xcd < r ? xcd * (q + 1) : r * (q + 1) + (xcd - r) * q) + lid;
    const int bnt = wg % NTN, bmt = wg / NTN;
    const int bm = bmt * BM, bn = bnt * BN;

    const int tid = threadIdx.x;
    const int wave = tid >> 6, lane = tid & 63;
    const int wm = wave >> 1;      // m-half 0..1 (64 nodes each)
    const int wn = wave & 1;       // n-half 0..1 (64 cols each)
    const int l15 = lane & 15, k8 = lane >> 4;

    floatx4 acc[4][4] = {};        // acc[nf][mf]: D[wcol][node]

    // A-side source select for K-tile kt (block-uniform)
    auto stage_a = [&](int kt, ushort* dst) {
        if (kt < 12) stage_rows(X, 384, kt * BK, dst, bm, M - 1, tid);
        else         stage_rows(AG, 768, (kt - 12) * BK, dst, bm, M - 1, tid);
    };

    // prologue: stage K-tiles 0,1 (8 loads/thread); wait kt0 landed
    stage_a(0, As[0]);
    stage_rows(BT, KC, 0, Bs[0], bn, D - 1, tid);
    stage_a(1, As[1]);
    stage_rows(BT, KC, BK, Bs[1], bn, D - 1, tid);
    WAIT_VM4();
    BAR();

    for (int j = 0; j < NKT; ++j) {
        const ushort* Ab = As[j % 3];
        const ushort* Bb = Bs[j % 3];

        short8 af[4], bf[4];
#pragma unroll
        for (int nf = 0; nf < 4; ++nf) {       // A-operand = weight rows
            const int rr = wn * 64 + nf * 16 + l15;
            af[nf] = *(const short8*)(Bb + rr * BK + ((k8 ^ ((rr >> 1) & 3)) << 3));
        }
#pragma unroll
        for (int mf = 0; mf < 4; ++mf) {       // B-operand = node rows
            const int rr = wm * 64 + mf * 16 + l15;
            bf[mf] = *(const short8*)(Ab + rr * BK + ((k8 ^ ((rr >> 1) & 3)) << 3));
        }

        const int js = j + 2;
        if (js < NKT) {                        // slot of tile j-1 (read done)
            stage_a(js, As[js % 3]);
            stage_rows(BT, KC, js * BK, Bs[js % 3], bn, D - 1, tid);
        }

        __builtin_amdgcn_s_setprio(1);
#pragma unroll
        for (int nf = 0; nf < 4; ++nf)
#pragma unroll
            for (int mf = 0; mf < 4; ++mf)
                acc[nf][mf] = __builtin_amdgcn_mfma_f32_16x16x32_bf16(
                    af[nf], bf[mf], acc[nf][mf], 0, 0, 0);
        __builtin_amdgcn_s_setprio(0);

        // counted drain: tile j+1 landed; keep tile j+2's 4 loads in flight
        if (j <= NKT - 3)      { WAIT_VM4(); }
        else if (j == NKT - 2) { WAIT_VM0(); }
        BAR();
    }

    // epilogue: lane (k8,l15) of frag (nf,mf) holds out-cols
    // bn + wn*64 + nf*16 + k8*4 + {0..3} of node bm + wm*64 + mf*16 + l15
    const int node0 = bm + wm * 64 + l15;
    const int colg = bn + wn * 64 + k8 * 4;
    float4 bv[4];
#pragma unroll
    for (int nf = 0; nf < 4; ++nf)
        bv[nf] = *(const float4*)(bias + colg + nf * 16);

#pragma unroll
    for (int mf = 0; mf < 4; ++mf) {
        const int node = node0 + mf * 16;
        if (node < M) {
            float v[4][4];
#pragma unroll
            for (int nf = 0; nf < 4; ++nf) {
                v[nf][0] = acc[nf][mf][0] + bv[nf].x;
                v[nf][1] = acc[nf][mf][1] + bv[nf].y;
                v[nf][2] = acc[nf][mf][2] + bv[nf].z;
                v[nf][3] = acc[nf][mf][3] + bv[nf].w;
                if (relu) {
#pragma unroll
                    for (int t = 0; t < 4; ++t) v[nf][t] = fmaxf(v[nf][t], 0.f);
                }
            }
            if (Xn) {
                uint2* rowp = (uint2*)(Xn + (size_t)node * D + colg);
#pragma unroll
                for (int nf = 0; nf < 4; ++nf) {
                    uint2 o2;
                    o2.x = pack2(v[nf][0], v[nf][1]);
                    o2.y = pack2(v[nf][2], v[nf][3]);
                    rowp[nf * 4] = o2;         // nf*16 cols = 4 uint2
                }
            } else {
                float4* rowp = (float4*)(outf + (size_t)node * D + colg);
#pragma unroll
                for (int nf = 0; nf < 4; ++nf)
                    rowp[nf * 4] = make_float4(v[nf][0], v[nf][1],
                                               v[nf][2], v[nf][3]);
            }
        }
    }
}

// ---- preprocessing: CSR by (rel, dst) ----

__global__ __launch_bounds__(256) void count_edges(
    const int* __restrict__ dst, const int* __restrict__ et,
    int* __restrict__ cntI, int E, int M)
{
    const int e = blockIdx.x * blockDim.x + threadIdx.x;
    if (e < E) atomicAdd(&cntI[(size_t)et[e] * M + dst[e]], 1);
}

__global__ __launch_bounds__(256) void finalize_cnt(
    const int* __restrict__ cntI, float* __restrict__ invc, int n)
{
    const int i = blockIdx.x * blockDim.x + threadIdx.x;
    if (i < n) invc[i] = 1.0f / (float)max(cntI[i], 1);
}

// ---- 3-kernel hierarchical exclusive scan (n ~ 100k) ----
__global__ __launch_bounds__(1024) void scan_local(
    const int* __restrict__ hist, int* __restrict__ offs,
    int* __restrict__ bsums, int n)
{
    __shared__ int tmp[1024];
    const int tid = threadIdx.x;
    const int i = blockIdx.x * 1024 + tid;
    const int v = (i < n) ? hist[i] : 0;
    tmp[tid] = v;
    __syncthreads();
#pragma unroll
    for (int off = 1; off < 1024; off <<= 1) {
        const int add = (tid >= off) ? tmp[tid - off] : 0;
        __syncthreads();
        tmp[tid] += add;
        __syncthreads();
    }
    if (i < n) offs[i] = tmp[tid] - v;
    if (tid == 1023) bsums[blockIdx.x] = tmp[1023];
}

__global__ __launch_bounds__(1024) void scan_bsums(
    int* __restrict__ bsums, int* __restrict__ total_out, int nb)
{
    __shared__ int tmp[1024];
    const int tid = threadIdx.x;
    const int v = (tid < nb) ? bsums[tid] : 0;
    tmp[tid] = v;
    __syncthreads();
#pragma unroll
    for (int off = 1; off < 1024; off <<= 1) {
        const int add = (tid >= off) ? tmp[tid - off] : 0;
        __syncthreads();
        tmp[tid] += add;
        __syncthreads();
    }
    if (tid < nb) bsums[tid] = tmp[tid] - v;
    if (tid == 1023) *total_out = tmp[1023];
}

__global__ __launch_bounds__(1024) void scan_add(
    int* __restrict__ offs, const int* __restrict__ bsums, int n)
{
    const int i = blockIdx.x * 1024 + threadIdx.x;
    if (i < n) offs[i] += bsums[blockIdx.x];
}

__global__ __launch_bounds__(256) void fill_sorted(
    const int* __restrict__ src, const int* __restrict__ dst,
    const int* __restrict__ et, const int* __restrict__ offs,
    int* __restrict__ cursor, int* __restrict__ sorted, int E, int M)
{
    const int e = blockIdx.x * blockDim.x + threadIdx.x;
    if (e < E) {
        const int key = et[e] * M + dst[e];
        const int pos = offs[key] + atomicAdd(&cursor[key], 1);
        sorted[pos] = src[e];
    }
}

// ---- weights -> BT bf16 [384 n-rows][1152 k-cols] per layer ----
// BT[n][k] = Wcat[k][n]; k<384: root, k<768: W[0], else W[1].
__global__ __launch_bounds__(256) void build_bt(
    const float* __restrict__ root1, const float* __restrict__ W1,
    const float* __restrict__ root2, const float* __restrict__ W2,
    const float* __restrict__ root3, const float* __restrict__ W3,
    ushort* __restrict__ BT)
{
    __shared__ float tile[32][33];
    const int l = blockIdx.z;
    const float* root = (l == 0) ? root1 : (l == 1) ? root2 : root3;
    const float* W    = (l == 0) ? W1    : (l == 1) ? W2    : W3;
    const int k0 = blockIdx.x * 32;   // K block (0..1151)
    const int n0 = blockIdx.y * 32;   // N block (0..383)
    const int tx = threadIdx.x & 31;
    const int ty = threadIdx.x >> 5;
    const float* srcm;
    int koff;
    if (k0 < D)          { srcm = root;      koff = 0; }
    else if (k0 < 2 * D) { srcm = W;         koff = D; }
    else                 { srcm = W + D * D; koff = 2 * D; }
#pragma unroll
    for (int i = 0; i < 4; ++i) {
        const int k = k0 - koff + ty + i * 8;
        tile[ty + i * 8][tx] = srcm[(size_t)k * D + n0 + tx];
    }
    __syncthreads();
    ushort* dst = BT + (size_t)l * D * KC;
#pragma unroll
    for (int i = 0; i < 4; ++i) {
        const int nn = n0 + ty + i * 8;
        const int kk = k0 + tx;
        dst[(size_t)nn * KC + kk] = f2bf(tile[tx][ty + i * 8]);
    }
}

__global__ __launch_bounds__(256) void cast_f32_to_bf16(
    const float* __restrict__ x, ushort* __restrict__ y, int n4)
{
    const int i = blockIdx.x * blockDim.x + threadIdx.x;
    if (i < n4) {
        const float4 v = ((const float4*)x)[i];
        uint2 o;
        o.x = pack2(v.x, v.y);
        o.y = pack2(v.z, v.w);
        ((uint2*)y)[i] = o;
    }
}

// ---- relation aggregation: one wave per node, mean over in-edges per rel ----
// Reads X [M,384] bf16 rows of sources; writes AG[d][r*384 + :] bf16.
__global__ __launch_bounds__(256) void aggregate_rel(
    const ushort* __restrict__ X, const int* __restrict__ sorted,
    const int* __restrict__ offs, const float* __restrict__ invc,
    ushort* __restrict__ AG, int M)
{
    const int wave = threadIdx.x >> 6;
    const int lane = threadIdx.x & 63;
    const int d = blockIdx.x * 4 + wave;
    if (d >= M) return;

#pragma unroll
    for (int r = 0; r < 2; ++r) {
        const int key = r * M + d;
        const int beg = offs[key], end = offs[key + 1];
        float g[6] = {0.f, 0.f, 0.f, 0.f, 0.f, 0.f};
        for (int i = beg; i < end; ++i) {
            const int s = sorted[i];
            const uint* tp = (const uint*)(X + (size_t)s * D);
#pragma unroll
            for (int p = 0; p < 3; ++p) {
                const uint b = tp[lane + 64 * p];
                g[2 * p]     += __uint_as_float(b << 16);
                g[2 * p + 1] += __uint_as_float(b & 0xffff0000u);
            }
        }
        const float ic = invc[key];
        uint* op = (uint*)(AG + (size_t)d * (2 * D) + r * D);
#pragma unroll
        for (int p = 0; p < 3; ++p)
            op[lane + 64 * p] = pack2(ic * g[2 * p], ic * g[2 * p + 1]);
    }
}

extern "C" void kernel_launch(void* const* d_in, const int* in_sizes, int n_in,
                              void* d_out, int out_size, void* d_ws, size_t ws_size,
                              hipStream_t stream)
{
    const float* emb   = (const float*)d_in[0];
    const int*   eidx  = (const int*)d_in[1];
    const int*   et    = (const int*)d_in[2];
    const float* W1    = (const float*)d_in[3];
    const float* root1 = (const float*)d_in[4];
    const float* bias1 = (const float*)d_in[5];
    const float* W2    = (const float*)d_in[6];
    const float* root2 = (const float*)d_in[7];
    const float* bias2 = (const float*)d_in[8];
    const float* W3    = (const float*)d_in[9];
    const float* root3 = (const float*)d_in[10];
    const float* bias3 = (const float*)d_in[11];

    float* out = (float*)d_out;
    const int M = in_sizes[0] / D;   // 50000
    const int E = in_sizes[1] / 2;   // 200000
    const int* src  = eidx;
    const int* dstv = eidx + E;

    const int n = 2 * M;
    const int nb = (n + 1023) / 1024;

    // Workspace: Xa[M*384]bf16 | Xb2[M*384]bf16 | AG[M*768]bf16 |
    //            BT[3*384*1152]bf16 | invcnt[2M]f32 | cntI[2M]i32 |
    //            offs[2M+1]i32 | sorted[E]i32 | bsums[nb]i32   (~158 MB)
    char* w = (char*)d_ws;
    ushort* Xa  = (ushort*)w;         w += (size_t)M * D * 2;
    ushort* Xb2 = (ushort*)w;         w += (size_t)M * D * 2;
    ushort* AG  = (ushort*)w;         w += (size_t)M * 2 * D * 2;
    ushort* BT  = (ushort*)w;         w += (size_t)3 * D * KC * 2;
    float* invcnt = (float*)w;        w += (size_t)n * 4;
    int* cntI = (int*)w;              w += (size_t)n * 4;
    int* offs = (int*)w;              w += ((size_t)n + 1) * 4;
    int* sorted = (int*)w;            w += (size_t)E * 4;
    int* bsums = (int*)w;

    // --- preprocessing ---
    hipMemsetAsync(cntI, 0, (size_t)n * sizeof(int), stream);
    count_edges<<<(E + 255) / 256, 256, 0, stream>>>(dstv, et, cntI, E, M);
    finalize_cnt<<<(n + 255) / 256, 256, 0, stream>>>(cntI, invcnt, n);
    scan_local<<<nb, 1024, 0, stream>>>(cntI, offs, bsums, n);
    scan_bsums<<<1, 1024, 0, stream>>>(bsums, offs + n, nb);
    scan_add<<<nb, 1024, 0, stream>>>(offs, bsums, n);
    hipMemsetAsync(cntI, 0, (size_t)n * sizeof(int), stream);
    fill_sorted<<<(E + 255) / 256, 256, 0, stream>>>(src, dstv, et, offs, cntI, sorted, E, M);

    build_bt<<<dim3(KC / 32, D / 32, 3), 256, 0, stream>>>(root1, W1, root2, W2, root3, W3, BT);
    cast_f32_to_bf16<<<(M * D / 4 + 255) / 256, 256, 0, stream>>>(emb, Xa, M * D / 4);

    // GEMM grid: 391 M-tiles x 3 N-tiles, bijective XCD swizzle in-kernel
    const int Mtiles = (M + BM - 1) / BM;
    const int nwg = Mtiles * NTN;
    const int agg_blocks = (M + 3) / 4;

    // Layer 1: X = Xa -> Xb2
    aggregate_rel<<<agg_blocks, 256, 0, stream>>>(Xa, sorted, offs, invcnt, AG, M);
    gemm_fused<<<nwg, 256, 0, stream>>>(Xa, AG, BT, bias1, Xb2, nullptr, M, nwg, 1);
    // Layer 2: Xb2 -> Xa
    aggregate_rel<<<agg_blocks, 256, 0, stream>>>(Xb2, sorted, offs, invcnt, AG, M);
    gemm_fused<<<nwg, 256, 0, stream>>>(Xb2, AG, BT + (size_t)D * KC, bias2, Xa, nullptr, M, nwg, 1);
    // Layer 3: Xa -> out (f32, no relu)
    aggregate_rel<<<agg_blocks, 256, 0, stream>>>(Xa, sorted, offs, invcnt, AG, M);
    gemm_fused<<<nwg, 256, 0, stream>>>(Xa, AG, BT + (size_t)2 * D * KC, bias3, nullptr, out, M, nwg, 0);
}